// Round 2
// baseline (204.800 us; speedup 1.0000x reference)
//
#include <hip/hip_runtime.h>
#include <math.h>

#define BB 256
#define KK 256
#define VV 256
#define MM 4000
#define TOPK 8

// K1: e64 = tanh(qk @ Wk^T + bk); qn64 = e64 / max(||e64||, 1e-8)   [f64 chain]
__global__ void k_proj(const float* __restrict__ qk, const float* __restrict__ Wk,
                       const float* __restrict__ bk, double* __restrict__ e64,
                       double* __restrict__ qn64) {
    int b = blockIdx.x, j = threadIdx.x;
    __shared__ float q[KK];
    __shared__ double red[256];
    q[j] = qk[b * KK + j];
    __syncthreads();
    const float* w = Wk + (size_t)j * KK;
    double acc = 0.0;
#pragma unroll 4
    for (int d = 0; d < KK; ++d) acc += (double)q[d] * (double)w[d];
    double val = tanh(acc + (double)bk[j]);
    e64[b * KK + j] = val;
    red[j] = val * val;
    __syncthreads();
    for (int s = 128; s > 0; s >>= 1) {
        if (j < s) red[j] += red[j + s];
        __syncthreads();
    }
    double nrm = fmax(sqrt(red[0]), 1e-8);
    qn64[b * KK + j] = val / nrm;
}

// K2: gather stored_keys = A[midx[m], k, 0]; kn64 = row / max(||row||, 1e-8)
__global__ void k_kn(const float* __restrict__ A, const int* __restrict__ midx,
                     double* __restrict__ kn64) {
    int m = blockIdx.x, t = threadIdx.x;
    size_t n = (size_t)midx[m];
    double val = (double)A[n * (size_t)(KK * VV) + (size_t)t * VV];
    __shared__ double red[256];
    red[t] = val * val;
    __syncthreads();
    for (int s = 128; s > 0; s >>= 1) {
        if (t < s) red[t] += red[t + s];
        __syncthreads();
    }
    double nrm = fmax(sqrt(red[0]), 1e-8);
    kn64[(size_t)m * KK + t] = val / nrm;
}

// K3: sims64 = qn64 @ kn64^T  (B x M), 16x16 LDS-tiled, f64
__global__ void k_sims(const double* __restrict__ qn, const double* __restrict__ kn,
                       double* __restrict__ sims) {
    int tx = threadIdx.x, ty = threadIdx.y;
    int m0 = blockIdx.x * 16, b0 = blockIdx.y * 16;
    __shared__ double qs[16][17], ks[16][17];
    double acc = 0.0;
    for (int kk = 0; kk < KK; kk += 16) {
        qs[ty][tx] = qn[(size_t)(b0 + ty) * KK + kk + tx];
        ks[ty][tx] = kn[(size_t)(m0 + ty) * KK + kk + tx];
        __syncthreads();
#pragma unroll
        for (int i = 0; i < 16; ++i) acc += qs[ty][i] * ks[tx][i];
        __syncthreads();
    }
    sims[(size_t)(b0 + ty) * MM + m0 + tx] = acc;
}

// K4: per-row top-8 (value desc, stable by index) in f64 + confidences
__global__ void k_topk(const double* __restrict__ sims, const int* __restrict__ midx,
                       const float* __restrict__ usage, float* __restrict__ out_conf,
                       float* __restrict__ out_sims, int* __restrict__ acts) {
    int b = blockIdx.x, t = threadIdx.x;
    double v[TOPK];
    int id[TOPK];
#pragma unroll
    for (int i = 0; i < TOPK; ++i) { v[i] = -INFINITY; id[i] = 0x7fffffff; }
    const double* row = sims + (size_t)b * MM;
    for (int m = t; m < MM; m += 256) {
        double x = row[m];
        if (x > v[TOPK - 1]) {
            v[TOPK - 1] = x; id[TOPK - 1] = m;
#pragma unroll
            for (int i = TOPK - 1; i > 0; --i) {
                if (v[i] > v[i - 1]) {  // strict: equal values keep smaller index first
                    double tv = v[i]; v[i] = v[i - 1]; v[i - 1] = tv;
                    int ti = id[i]; id[i] = id[i - 1]; id[i - 1] = ti;
                }
            }
        }
    }
    __shared__ double sv[256 * TOPK];
    __shared__ int si[256 * TOPK];
#pragma unroll
    for (int i = 0; i < TOPK; ++i) { sv[t * TOPK + i] = v[i]; si[t * TOPK + i] = id[i]; }
    __syncthreads();
    for (int stride = 128; stride > 0; stride >>= 1) {
        if (t < stride) {
            double* av = &sv[t * TOPK];
            int*    ai = &si[t * TOPK];
            double* bv = &sv[(t + stride) * TOPK];
            int*    bi = &si[(t + stride) * TOPK];
            double mv[TOPK]; int mi[TOPK];
            int pa = 0, pb = 0;
#pragma unroll
            for (int i = 0; i < TOPK; ++i) {
                double va = av[pa], vb = bv[pb];
                bool takeA = (va > vb) || (va == vb && ai[pa] < bi[pb]);
                if (takeA) { mv[i] = va; mi[i] = ai[pa]; ++pa; }
                else       { mv[i] = vb; mi[i] = bi[pb]; ++pb; }
            }
#pragma unroll
            for (int i = 0; i < TOPK; ++i) { av[i] = mv[i]; ai[i] = mi[i]; }
        }
        __syncthreads();
    }
    if (t < TOPK) {
        double val = sv[t];
        int idx = si[t];
        int actual = midx[idx];
        out_sims[b * TOPK + t] = (float)val;
        out_conf[b * TOPK + t] = (float)(val * (1.0 + log1p((double)usage[actual])));
        acts[b * TOPK + t] = actual;
    }
}

// K5: retrieved[b,k,v] = sum_d e[b,d] * A[actual[b,k], d, v]   (f32, HBM-bound)
__global__ void k_retr(const float* __restrict__ A, const double* __restrict__ e64,
                       const int* __restrict__ acts, float* __restrict__ out) {
    int bk_ = blockIdx.x;       // b*TOPK + k
    int b = bk_ >> 3;
    int v = threadIdx.x;
    size_t n = (size_t)acts[bk_];
    const float* Ap = A + n * (size_t)(KK * VV) + v;
    __shared__ float es[KK];
    es[v] = (float)e64[b * KK + v];
    __syncthreads();
    float acc = 0.f;
#pragma unroll 8
    for (int d = 0; d < KK; ++d) acc = fmaf(es[d], Ap[(size_t)d * VV], acc);
    out[(size_t)bk_ * VV + v] = acc;
}

extern "C" void kernel_launch(void* const* d_in, const int* in_sizes, int n_in,
                              void* d_out, int out_size, void* d_ws, size_t ws_size,
                              hipStream_t stream) {
    const float* qk    = (const float*)d_in[0];
    const float* Wk    = (const float*)d_in[1];
    const float* bk    = (const float*)d_in[2];
    const float* A     = (const float*)d_in[3];
    const float* usage = (const float*)d_in[4];
    const int*   midx  = (const int*)d_in[5];

    float* out   = (float*)d_out;
    float* retr  = out;                                 // B*TOPK*V = 524288
    float* conf  = out + (size_t)BB * TOPK * VV;        // 2048
    float* tsims = conf + BB * TOPK;                    // 2048

    double* ws64  = (double*)d_ws;
    double* e64   = ws64;                               // 65536 doubles
    double* qn64  = e64 + BB * KK;                      // 65536
    double* kn64  = qn64 + BB * KK;                     // 1,024,000
    double* sims  = kn64 + (size_t)MM * KK;             // 1,024,000
    int*    acts  = (int*)(sims + (size_t)BB * MM);     // 2048 ints

    k_proj<<<BB, 256, 0, stream>>>(qk, Wk, bk, e64, qn64);
    k_kn<<<MM, 256, 0, stream>>>(A, midx, kn64);
    dim3 g3(MM / 16, BB / 16), b3(16, 16);
    k_sims<<<g3, b3, 0, stream>>>(qn64, kn64, sims);
    k_topk<<<BB, 256, 0, stream>>>(sims, midx, usage, conf, tsims, acts);
    k_retr<<<BB * TOPK, 256, 0, stream>>>(A, e64, acts, retr);
}

// Round 4
// 175.268 us; speedup vs baseline: 1.1685x; 1.1685x over previous
//
#include <hip/hip_runtime.h>
#include <math.h>

#define BB 256
#define KK 256
#define VV 256
#define MM 4000
#define TOPK 8

// K1: e64 = tanh(qk @ Wk^T + bk); qn64 = e64 / max(||e64||, 1e-8)   [f64 chain]
// (verbatim from the round-2 PASSED kernel)
__global__ void k_proj(const float* __restrict__ qk, const float* __restrict__ Wk,
                       const float* __restrict__ bk, double* __restrict__ e64,
                       double* __restrict__ qn64) {
    int b = blockIdx.x, j = threadIdx.x;
    __shared__ float q[KK];
    __shared__ double red[256];
    q[j] = qk[b * KK + j];
    __syncthreads();
    const float* w = Wk + (size_t)j * KK;
    double acc = 0.0;
#pragma unroll 4
    for (int d = 0; d < KK; ++d) acc += (double)q[d] * (double)w[d];
    double val = tanh(acc + (double)bk[j]);
    e64[b * KK + j] = val;
    red[j] = val * val;
    __syncthreads();
    for (int s = 128; s > 0; s >>= 1) {
        if (j < s) red[j] += red[j + s];
        __syncthreads();
    }
    double nrm = fmax(sqrt(red[0]), 1e-8);
    qn64[b * KK + j] = val / nrm;
}

// K2: gather stored_keys = A[midx[m], k, 0]; kn64 = row / max(||row||, 1e-8)
// (verbatim from round-2 PASSED kernel)
__global__ void k_kn(const float* __restrict__ A, const int* __restrict__ midx,
                     double* __restrict__ kn64) {
    int m = blockIdx.x, t = threadIdx.x;
    size_t n = (size_t)midx[m];
    double val = (double)A[n * (size_t)(KK * VV) + (size_t)t * VV];
    __shared__ double red[256];
    red[t] = val * val;
    __syncthreads();
    for (int s = 128; s > 0; s >>= 1) {
        if (t < s) red[t] += red[t + s];
        __syncthreads();
    }
    double nrm = fmax(sqrt(red[0]), 1e-8);
    kn64[(size_t)m * KK + t] = val / nrm;
}

// K3: sims64 = qn64 @ kn64^T (B x M), f64, 32x32 tile, 2x2 register blocking.
// Structure exonerated by the r1/r3 absmax-identity argument; dtype from the
// passed r2 config. Halves LDS reads per FMA vs the 16x16 1-output version.
__global__ void __launch_bounds__(256) k_sims(
        const double* __restrict__ qn, const double* __restrict__ kn,
        double* __restrict__ sims) {
    int tx = threadIdx.x, ty = threadIdx.y;   // 16x16
    int tid = ty * 16 + tx;
    int m0 = blockIdx.x * 32, b0 = blockIdx.y * 32;
    __shared__ double qs[32][33], ks[32][33];
    double a00 = 0.0, a01 = 0.0, a10 = 0.0, a11 = 0.0;
    for (int kk = 0; kk < KK; kk += 32) {
#pragma unroll
        for (int i = 0; i < 4; ++i) {
            int idx = tid + i * 256;          // 0..1023
            int r = idx >> 5, c = idx & 31;
            qs[r][c] = qn[(size_t)(b0 + r) * KK + kk + c];
            ks[r][c] = kn[(size_t)(m0 + r) * KK + kk + c];
        }
        __syncthreads();
#pragma unroll
        for (int i = 0; i < 32; ++i) {
            double q0 = qs[ty][i], q1 = qs[ty + 16][i];
            double k0 = ks[tx][i], k1 = ks[tx + 16][i];
            a00 += q0 * k0; a01 += q0 * k1;
            a10 += q1 * k0; a11 += q1 * k1;
        }
        __syncthreads();
    }
    sims[(size_t)(b0 + ty) * MM + m0 + tx]           = a00;
    sims[(size_t)(b0 + ty) * MM + m0 + tx + 16]      = a01;
    sims[(size_t)(b0 + ty + 16) * MM + m0 + tx]      = a10;
    sims[(size_t)(b0 + ty + 16) * MM + m0 + tx + 16] = a11;
}

// K4: per-row top-8 (value desc, stable by index) in f64 + confidences
// (verbatim from round-2 PASSED kernel)
__global__ void k_topk(const double* __restrict__ sims, const int* __restrict__ midx,
                       const float* __restrict__ usage, float* __restrict__ out_conf,
                       float* __restrict__ out_sims, int* __restrict__ acts) {
    int b = blockIdx.x, t = threadIdx.x;
    double v[TOPK];
    int id[TOPK];
#pragma unroll
    for (int i = 0; i < TOPK; ++i) { v[i] = -INFINITY; id[i] = 0x7fffffff; }
    const double* row = sims + (size_t)b * MM;
    for (int m = t; m < MM; m += 256) {
        double x = row[m];
        if (x > v[TOPK - 1]) {
            v[TOPK - 1] = x; id[TOPK - 1] = m;
#pragma unroll
            for (int i = TOPK - 1; i > 0; --i) {
                if (v[i] > v[i - 1]) {  // strict: equal values keep smaller index first
                    double tv = v[i]; v[i] = v[i - 1]; v[i - 1] = tv;
                    int ti = id[i]; id[i] = id[i - 1]; id[i - 1] = ti;
                }
            }
        }
    }
    __shared__ double sv[256 * TOPK];
    __shared__ int si[256 * TOPK];
#pragma unroll
    for (int i = 0; i < TOPK; ++i) { sv[t * TOPK + i] = v[i]; si[t * TOPK + i] = id[i]; }
    __syncthreads();
    for (int stride = 128; stride > 0; stride >>= 1) {
        if (t < stride) {
            double* av = &sv[t * TOPK];
            int*    ai = &si[t * TOPK];
            double* bv = &sv[(t + stride) * TOPK];
            int*    bi = &si[(t + stride) * TOPK];
            double mv[TOPK]; int mi[TOPK];
            int pa = 0, pb = 0;
#pragma unroll
            for (int i = 0; i < TOPK; ++i) {
                double va = av[pa], vb = bv[pb];
                bool takeA = (va > vb) || (va == vb && ai[pa] < bi[pb]);
                if (takeA) { mv[i] = va; mi[i] = ai[pa]; ++pa; }
                else       { mv[i] = vb; mi[i] = bi[pb]; ++pb; }
            }
#pragma unroll
            for (int i = 0; i < TOPK; ++i) { av[i] = mv[i]; ai[i] = mi[i]; }
        }
        __syncthreads();
    }
    if (t < TOPK) {
        double val = sv[t];
        int idx = si[t];
        int actual = midx[idx];
        out_sims[b * TOPK + t] = (float)val;
        out_conf[b * TOPK + t] = (float)(val * (1.0 + log1p((double)usage[actual])));
        acts[b * TOPK + t] = actual;
    }
}

// K5: retrieved[b,k,v] = sum_d e[b,d] * A[acts[b,k], d, v]
// float4 loads (1 KB/wave-instr), 4 waves split the d-range, LDS reduce.
// (structure exonerated by the r1/r3 absmax-identity argument)
__global__ void __launch_bounds__(256) k_retr(
        const float* __restrict__ A, const double* __restrict__ e64,
        const int* __restrict__ acts, float* __restrict__ out) {
    int bk_ = blockIdx.x;        // b*TOPK + k
    int b = bk_ >> 3;
    int tid = threadIdx.x;
    int w = tid >> 6, l = tid & 63;
    size_t n = (size_t)acts[bk_];
    const float* Ap = A + n * (size_t)(KK * VV);
    __shared__ float es[KK];
    __shared__ float part[4][64][4];
    es[tid] = (float)e64[b * KK + tid];
    __syncthreads();
    float ax = 0.f, ay = 0.f, az = 0.f, aw = 0.f;
    const float* base = Ap + (size_t)(w * 64) * VV + 4 * l;
#pragma unroll 8
    for (int dd = 0; dd < 64; ++dd) {
        float ev = es[w * 64 + dd];
        const float4 a = *reinterpret_cast<const float4*>(base + (size_t)dd * VV);
        ax = fmaf(ev, a.x, ax); ay = fmaf(ev, a.y, ay);
        az = fmaf(ev, a.z, az); aw = fmaf(ev, a.w, aw);
    }
    part[w][l][0] = ax; part[w][l][1] = ay; part[w][l][2] = az; part[w][l][3] = aw;
    __syncthreads();
    int l2 = tid >> 2, j = tid & 3;
    float s = part[0][l2][j] + part[1][l2][j] + part[2][l2][j] + part[3][l2][j];
    out[(size_t)bk_ * VV + tid] = s;   // 4*l2 + j == tid
}

extern "C" void kernel_launch(void* const* d_in, const int* in_sizes, int n_in,
                              void* d_out, int out_size, void* d_ws, size_t ws_size,
                              hipStream_t stream) {
    const float* qk    = (const float*)d_in[0];
    const float* Wk    = (const float*)d_in[1];
    const float* bk    = (const float*)d_in[2];
    const float* A     = (const float*)d_in[3];
    const float* usage = (const float*)d_in[4];
    const int*   midx  = (const int*)d_in[5];

    float* out   = (float*)d_out;
    float* retr  = out;                                 // B*TOPK*V = 524288
    float* conf  = out + (size_t)BB * TOPK * VV;        // 2048
    float* tsims = conf + BB * TOPK;                    // 2048

    // workspace layout: identical to the round-2 PASSED layout (17.44 MB)
    double* ws64  = (double*)d_ws;
    double* e64   = ws64;                               // 65536 doubles
    double* qn64  = e64 + BB * KK;                      // 65536
    double* kn64  = qn64 + BB * KK;                     // 1,024,000
    double* sims  = kn64 + (size_t)MM * KK;             // 1,024,000
    int*    acts  = (int*)(sims + (size_t)BB * MM);     // 2048 ints

    k_proj<<<BB, 256, 0, stream>>>(qk, Wk, bk, e64, qn64);
    k_kn<<<MM, 256, 0, stream>>>(A, midx, kn64);
    dim3 g3(MM / 32, BB / 32), b3(16, 16);
    k_sims<<<g3, b3, 0, stream>>>(qn64, kn64, sims);
    k_topk<<<BB, 256, 0, stream>>>(sims, midx, usage, conf, tsims, acts);
    k_retr<<<BB * TOPK, 256, 0, stream>>>(A, e64, acts, retr);
}